// Round 4
// baseline (104.555 us; speedup 1.0000x reference)
//
#include <hip/hip_runtime.h>
#include <math.h>

#define NTAB 512             // table intervals; table has NTAB+1 = 513 entries
#define TLIM 8.0f            // t range [-TLIM, TLIM]
#define NBUILD 129           // builder blocks (4 entries each -> covers 513)

// Fused kernel, grid = 1024 blocks x 256 threads.
// LDS = 33.3 KB -> 4 blocks/CU x 256 CUs = whole grid co-resident, so the
// producer->consumer spin below cannot deadlock regardless of dispatch order.
// Blocks 0..128 build the LUT (one wave per entry), publish via agent-scope
// stores + release atomicAdd on a counter in d_ws; ALL blocks first issue
// their x loads (16 MB stream overlaps the build), then acquire-spin, stage
// the table to LDS, lerp, write.
__global__ __launch_bounds__(256) void fused_kernel(
    const float4* __restrict__ x4,
    const float* __restrict__ convw, const float* __restrict__ convb,
    const float* __restrict__ e0w, const float* __restrict__ e0b,
    const float* __restrict__ e1w, const float* __restrict__ e1b,
    const float* __restrict__ e2w, const float* __restrict__ e2b,
    const float* __restrict__ fmw, const float* __restrict__ fmb,
    const float* __restrict__ c1w, const float* __restrict__ c1b,
    const float* __restrict__ p1w, const float* __restrict__ p1b,
    const float* __restrict__ c2w, const float* __restrict__ c2b,
    const float* __restrict__ p2w, const float* __restrict__ p2b,
    const float* __restrict__ c3w, const float* __restrict__ c3b,
    const float* __restrict__ hw,  const float* __restrict__ hb,
    unsigned int* __restrict__ counter,   // d_ws + 0 (memset to 0 pre-launch)
    float* __restrict__ tab,              // d_ws + 64
    float2* __restrict__ out2)
{
    __shared__ union {
        float  wt[128 * 65];              // build phase: e1_w transposed
        float2 ltab[NTAB + 1];            // eval phase: (value, delta)
    } sh;

    const int tid  = threadIdx.x;
    const int bid  = blockIdx.x;
    const int base = bid * 1024;          // 1024 samples per block

    // ---- issue x loads first: 16 MB stream overlaps build/spin ----
    float4 xs[4];
    #pragma unroll
    for (int j = 0; j < 4; ++j)
        xs[j] = x4[base + j * 256 + tid];

    // ---------------- build phase (blocks 0..NBUILD-1) ----------------
    if (bid < NBUILD) {
        // Stage e1_w (64x128) transposed into LDS, stride 65 (conflict-free).
        #pragma unroll
        for (int i = 0; i < 32; ++i) {
            int idx = i * 256 + tid;      // 0..8191
            int j = idx >> 7;             // row 0..63
            int k = idx & 127;            // col 0..127
            sh.wt[k * 65 + j] = e1w[idx];
        }
        __syncthreads();

        const int wave = tid >> 6;
        const int lane = tid & 63;
        const int e    = bid * 4 + wave;          // table entry (may be >NTAB)
        const int ec   = (e <= NTAB) ? e : NTAB;  // clamp so math is uniform

        const float t  = -TLIM + (2.0f * TLIM) * (float)ec / (float)NTAB;
        const float sv = 1.0f / (1.0f + expf(-t));

        // h2[lane] = relu(sum_k e1w[lane,k]*relu(e0w[k]*sv+e0b[k]) + e1b[lane])
        float a0 = e1b[lane], a1 = 0.0f, a2 = 0.0f, a3 = 0.0f;
        #pragma unroll 4
        for (int k = 0; k < 128; k += 4) {
            float h10 = fmaxf(fmaf(e0w[k + 0], sv, e0b[k + 0]), 0.0f);
            float h11 = fmaxf(fmaf(e0w[k + 1], sv, e0b[k + 1]), 0.0f);
            float h12 = fmaxf(fmaf(e0w[k + 2], sv, e0b[k + 2]), 0.0f);
            float h13 = fmaxf(fmaf(e0w[k + 3], sv, e0b[k + 3]), 0.0f);
            a0 = fmaf(sh.wt[(k + 0) * 65 + lane], h10, a0);
            a1 = fmaf(sh.wt[(k + 1) * 65 + lane], h11, a1);
            a2 = fmaf(sh.wt[(k + 2) * 65 + lane], h12, a2);
            a3 = fmaf(sh.wt[(k + 3) * 65 + lane], h13, a3);
        }
        float h2 = fmaxf((a0 + a1) + (a2 + a3), 0.0f);

        // latent = e2_w (2x64) @ h2 + e2_b : butterfly reduction
        float v0 = e2w[lane] * h2;
        float v1 = e2w[64 + lane] * h2;
        #pragma unroll
        for (int off = 32; off > 0; off >>= 1) {
            v0 += __shfl_xor(v0, off);
            v1 += __shfl_xor(v1, off);
        }
        float l0 = v0 + e2b[0];
        float l1 = v1 + e2b[1];

        // QCNN tanh chain
        float y0[4], y1[4], y2[3], y3[2];
        #pragma unroll
        for (int o = 0; o < 4; ++o)
            y0[o] = tanhf(fmaf(fmw[o*2], l0, fmaf(fmw[o*2+1], l1, fmb[o])));
        #pragma unroll
        for (int o = 0; o < 4; ++o)
            y1[o] = tanhf(fmaf(c1w[o*4], y0[0], fmaf(c1w[o*4+1], y0[1],
                          fmaf(c1w[o*4+2], y0[2], fmaf(c1w[o*4+3], y0[3], c1b[o])))));
        #pragma unroll
        for (int o = 0; o < 3; ++o)
            y2[o] = tanhf(fmaf(p1w[o*4], y1[0], fmaf(p1w[o*4+1], y1[1],
                          fmaf(p1w[o*4+2], y1[2], fmaf(p1w[o*4+3], y1[3], p1b[o])))));
        #pragma unroll
        for (int o = 0; o < 2; ++o)
            y3[o] = tanhf(fmaf(c2w[o*3], y2[0], fmaf(c2w[o*3+1], y2[1],
                          fmaf(c2w[o*3+2], y2[2], c2b[o]))));
        float y4 = tanhf(fmaf(p2w[0], y3[0], fmaf(p2w[1], y3[1], p2b[0])));
        float y5 = tanhf(fmaf(c3w[0], y4, c3b[0]));
        float g0 = fmaf(hw[0], y5, hb[0]);
        float g1 = fmaf(hw[1], y5, hb[1]);
        float p0 = 1.0f / (1.0f + expf(g1 - g0));   // softmax -> sigmoid(g0-g1)

        if (lane == 0 && e <= NTAB)
            __hip_atomic_store(&tab[e], p0, __ATOMIC_RELAXED,
                               __HIP_MEMORY_SCOPE_AGENT);
        __syncthreads();                  // all waves' stores issued, wt dead
        if (tid == 0) {
            __threadfence();              // belt & braces before release
            __hip_atomic_fetch_add(counter, 1u, __ATOMIC_RELEASE,
                                   __HIP_MEMORY_SCOPE_AGENT);
        }
    }

    // ---------------- wait for full table ----------------
    if (tid == 0) {
        while (__hip_atomic_load(counter, __ATOMIC_ACQUIRE,
                                 __HIP_MEMORY_SCOPE_AGENT) < NBUILD)
            __builtin_amdgcn_s_sleep(2);
    }
    __syncthreads();

    // ---------------- stage table to LDS as (value, delta) ----------------
    for (int i = tid; i < NTAB + 1; i += 256) {
        float v  = __hip_atomic_load(&tab[i], __ATOMIC_RELAXED,
                                     __HIP_MEMORY_SCOPE_AGENT);
        float vn = v;
        if (i < NTAB)
            vn = __hip_atomic_load(&tab[i + 1], __ATOMIC_RELAXED,
                                   __HIP_MEMORY_SCOPE_AGENT);
        sh.ltab[i] = make_float2(v, vn - v);
    }
    __syncthreads();

    // ---------------- eval: 4 samples per thread ----------------
    const float w0 = convw[0], w1 = convw[1], w2 = convw[2], w3 = convw[3];
    const float cb = convb[0];
    const float scale = (float)NTAB / (2.0f * TLIM);   // 32.0f

    #pragma unroll
    for (int j = 0; j < 4; ++j) {
        float t = fmaf(xs[j].x, w0, fmaf(xs[j].y, w1,
                  fmaf(xs[j].z, w2, fmaf(xs[j].w, w3, cb))));
        float f = fminf(fmaxf((t + TLIM) * scale, 0.0f), (float)NTAB - 0.001f);
        int   k = (int)f;
        float r = f - (float)k;
        float2 vd = sh.ltab[k];
        float p = fmaf(r, vd.y, vd.x);
        out2[base + j * 256 + tid] = make_float2(p, 1.0f - p);
    }
}

extern "C" void kernel_launch(void* const* d_in, const int* in_sizes, int n_in,
                              void* d_out, int out_size, void* d_ws, size_t ws_size,
                              hipStream_t stream) {
    const float* x     = (const float*)d_in[0];
    const float* convw = (const float*)d_in[1];
    const float* convb = (const float*)d_in[2];
    const float* e0w   = (const float*)d_in[3];
    const float* e0b   = (const float*)d_in[4];
    const float* e1w   = (const float*)d_in[5];
    const float* e1b   = (const float*)d_in[6];
    const float* e2w   = (const float*)d_in[7];
    const float* e2b   = (const float*)d_in[8];
    const float* fmw   = (const float*)d_in[9];
    const float* fmb   = (const float*)d_in[10];
    const float* c1w   = (const float*)d_in[11];
    const float* c1b   = (const float*)d_in[12];
    const float* p1w   = (const float*)d_in[13];
    const float* p1b   = (const float*)d_in[14];
    const float* c2w   = (const float*)d_in[15];
    const float* c2b   = (const float*)d_in[16];
    const float* p2w   = (const float*)d_in[17];
    const float* p2b   = (const float*)d_in[18];
    const float* c3w   = (const float*)d_in[19];
    const float* c3b   = (const float*)d_in[20];
    const float* hw    = (const float*)d_in[21];
    const float* hb    = (const float*)d_in[22];

    unsigned int* counter = (unsigned int*)d_ws;          // 4 B used
    float*        tab     = (float*)((char*)d_ws + 64);   // 513 floats

    const int B = in_sizes[0] / 4;                        // 1048576 samples

    // Reset the producer counter every call (captured, deterministic).
    hipMemsetAsync(d_ws, 0, 64, stream);

    int nblocks = B / 1024;                               // 1024
    fused_kernel<<<nblocks, 256, 0, stream>>>(
        (const float4*)x, convw, convb,
        e0w, e0b, e1w, e1b, e2w, e2b, fmw, fmb, c1w, c1b,
        p1w, p1b, c2w, c2b, p2w, p2b, c3w, c3b, hw, hb,
        counter, tab, (float2*)d_out);
}

// Round 5
// 30.416 us; speedup vs baseline: 3.4375x; 3.4375x over previous
//
#include <hip/hip_runtime.h>
#include <math.h>

#define NTAB 512             // table intervals; table has NTAB+1 = 513 entries
#define TLIM 8.0f            // t range [-TLIM, TLIM]
#define NBUILD 129           // builder blocks (4 entries each -> covers 513)

// Fused kernel, grid = 1024 blocks x 256 threads, LDS 33.3 KB -> 4 blocks/CU
// x 256 CUs = whole grid co-resident (spin cannot deadlock).
// Handshake uses ONLY relaxed agent-scope atomics (remote ops at the
// coherence point) -- no acquire/release, so NO buffer_inv / buffer_wbl2
// L2 maintenance in the loop (that was the 100us regression in round 4).
__global__ __launch_bounds__(256) void fused_kernel(
    const float4* __restrict__ x4,
    const float* __restrict__ convw, const float* __restrict__ convb,
    const float* __restrict__ e0w, const float* __restrict__ e0b,
    const float* __restrict__ e1w, const float* __restrict__ e1b,
    const float* __restrict__ e2w, const float* __restrict__ e2b,
    const float* __restrict__ fmw, const float* __restrict__ fmb,
    const float* __restrict__ c1w, const float* __restrict__ c1b,
    const float* __restrict__ p1w, const float* __restrict__ p1b,
    const float* __restrict__ c2w, const float* __restrict__ c2b,
    const float* __restrict__ p2w, const float* __restrict__ p2b,
    const float* __restrict__ c3w, const float* __restrict__ c3b,
    const float* __restrict__ hw,  const float* __restrict__ hb,
    unsigned int* __restrict__ counter,   // d_ws + 0 (memset to 0 pre-launch)
    float* __restrict__ tab,              // d_ws + 64
    float2* __restrict__ out2)
{
    __shared__ union {
        float  wt[128 * 65];              // build phase: e1_w transposed
        float2 ltab[NTAB + 1];            // eval phase: (value, delta)
    } sh;

    const int tid  = threadIdx.x;
    const int bid  = blockIdx.x;
    const int base = bid * 1024;          // 1024 samples per block

    // ---- issue x loads first: 16 MB stream overlaps build/spin ----
    float4 xs[4];
    #pragma unroll
    for (int j = 0; j < 4; ++j)
        xs[j] = x4[base + j * 256 + tid];

    // ---------------- build phase (blocks 0..NBUILD-1) ----------------
    if (bid < NBUILD) {
        // Stage e1_w (64x128) transposed into LDS, stride 65 (conflict-free).
        #pragma unroll
        for (int i = 0; i < 32; ++i) {
            int idx = i * 256 + tid;      // 0..8191
            int j = idx >> 7;             // row 0..63
            int k = idx & 127;            // col 0..127
            sh.wt[k * 65 + j] = e1w[idx];
        }
        __syncthreads();

        const int wave = tid >> 6;
        const int lane = tid & 63;
        const int e    = bid * 4 + wave;          // table entry (may be >NTAB)
        const int ec   = (e <= NTAB) ? e : NTAB;  // clamp so math is uniform

        const float t  = -TLIM + (2.0f * TLIM) * (float)ec / (float)NTAB;
        const float sv = 1.0f / (1.0f + expf(-t));

        // h2[lane] = relu(sum_k e1w[lane,k]*relu(e0w[k]*sv+e0b[k]) + e1b[lane])
        float a0 = e1b[lane], a1 = 0.0f, a2 = 0.0f, a3 = 0.0f;
        #pragma unroll 4
        for (int k = 0; k < 128; k += 4) {
            float h10 = fmaxf(fmaf(e0w[k + 0], sv, e0b[k + 0]), 0.0f);
            float h11 = fmaxf(fmaf(e0w[k + 1], sv, e0b[k + 1]), 0.0f);
            float h12 = fmaxf(fmaf(e0w[k + 2], sv, e0b[k + 2]), 0.0f);
            float h13 = fmaxf(fmaf(e0w[k + 3], sv, e0b[k + 3]), 0.0f);
            a0 = fmaf(sh.wt[(k + 0) * 65 + lane], h10, a0);
            a1 = fmaf(sh.wt[(k + 1) * 65 + lane], h11, a1);
            a2 = fmaf(sh.wt[(k + 2) * 65 + lane], h12, a2);
            a3 = fmaf(sh.wt[(k + 3) * 65 + lane], h13, a3);
        }
        float h2 = fmaxf((a0 + a1) + (a2 + a3), 0.0f);

        // latent = e2_w (2x64) @ h2 + e2_b : butterfly reduction
        float v0 = e2w[lane] * h2;
        float v1 = e2w[64 + lane] * h2;
        #pragma unroll
        for (int off = 32; off > 0; off >>= 1) {
            v0 += __shfl_xor(v0, off);
            v1 += __shfl_xor(v1, off);
        }
        float l0 = v0 + e2b[0];
        float l1 = v1 + e2b[1];

        // QCNN tanh chain
        float y0[4], y1[4], y2[3], y3[2];
        #pragma unroll
        for (int o = 0; o < 4; ++o)
            y0[o] = tanhf(fmaf(fmw[o*2], l0, fmaf(fmw[o*2+1], l1, fmb[o])));
        #pragma unroll
        for (int o = 0; o < 4; ++o)
            y1[o] = tanhf(fmaf(c1w[o*4], y0[0], fmaf(c1w[o*4+1], y0[1],
                          fmaf(c1w[o*4+2], y0[2], fmaf(c1w[o*4+3], y0[3], c1b[o])))));
        #pragma unroll
        for (int o = 0; o < 3; ++o)
            y2[o] = tanhf(fmaf(p1w[o*4], y1[0], fmaf(p1w[o*4+1], y1[1],
                          fmaf(p1w[o*4+2], y1[2], fmaf(p1w[o*4+3], y1[3], p1b[o])))));
        #pragma unroll
        for (int o = 0; o < 2; ++o)
            y3[o] = tanhf(fmaf(c2w[o*3], y2[0], fmaf(c2w[o*3+1], y2[1],
                          fmaf(c2w[o*3+2], y2[2], c2b[o]))));
        float y4 = tanhf(fmaf(p2w[0], y3[0], fmaf(p2w[1], y3[1], p2b[0])));
        float y5 = tanhf(fmaf(c3w[0], y4, c3b[0]));
        float g0 = fmaf(hw[0], y5, hb[0]);
        float g1 = fmaf(hw[1], y5, hb[1]);
        float p0 = 1.0f / (1.0f + expf(g1 - g0));   // softmax -> sigmoid(g0-g1)

        if (lane == 0 && e <= NTAB)
            __hip_atomic_store(&tab[e], p0, __ATOMIC_RELAXED,
                               __HIP_MEMORY_SCOPE_AGENT);
        // Drain this wave's store to the coherence point, then block-sync,
        // then a RELAXED add publishes completion (no L2 writeback).
        asm volatile("s_waitcnt vmcnt(0)" ::: "memory");
        __syncthreads();
        if (tid == 0)
            __hip_atomic_fetch_add(counter, 1u, __ATOMIC_RELAXED,
                                   __HIP_MEMORY_SCOPE_AGENT);
    }

    // ---------------- wait for full table (relaxed polls only) ----------------
    if (tid == 0) {
        while (__hip_atomic_load(counter, __ATOMIC_RELAXED,
                                 __HIP_MEMORY_SCOPE_AGENT) < NBUILD)
            __builtin_amdgcn_s_sleep(8);
    }
    __syncthreads();

    // ---- stage table to LDS as (value, delta); relaxed coherent reads ----
    for (int i = tid; i < NTAB + 1; i += 256) {
        float v  = __hip_atomic_load(&tab[i], __ATOMIC_RELAXED,
                                     __HIP_MEMORY_SCOPE_AGENT);
        float vn = v;
        if (i < NTAB)
            vn = __hip_atomic_load(&tab[i + 1], __ATOMIC_RELAXED,
                                   __HIP_MEMORY_SCOPE_AGENT);
        sh.ltab[i] = make_float2(v, vn - v);
    }
    __syncthreads();

    // ---------------- eval: 4 samples per thread ----------------
    const float w0 = convw[0], w1 = convw[1], w2 = convw[2], w3 = convw[3];
    const float cb = convb[0];
    const float scale = (float)NTAB / (2.0f * TLIM);   // 32.0f

    #pragma unroll
    for (int j = 0; j < 4; ++j) {
        float t = fmaf(xs[j].x, w0, fmaf(xs[j].y, w1,
                  fmaf(xs[j].z, w2, fmaf(xs[j].w, w3, cb))));
        float f = fminf(fmaxf((t + TLIM) * scale, 0.0f), (float)NTAB - 0.001f);
        int   k = (int)f;
        float r = f - (float)k;
        float2 vd = sh.ltab[k];
        float p = fmaf(r, vd.y, vd.x);
        out2[base + j * 256 + tid] = make_float2(p, 1.0f - p);
    }
}

extern "C" void kernel_launch(void* const* d_in, const int* in_sizes, int n_in,
                              void* d_out, int out_size, void* d_ws, size_t ws_size,
                              hipStream_t stream) {
    const float* x     = (const float*)d_in[0];
    const float* convw = (const float*)d_in[1];
    const float* convb = (const float*)d_in[2];
    const float* e0w   = (const float*)d_in[3];
    const float* e0b   = (const float*)d_in[4];
    const float* e1w   = (const float*)d_in[5];
    const float* e1b   = (const float*)d_in[6];
    const float* e2w   = (const float*)d_in[7];
    const float* e2b   = (const float*)d_in[8];
    const float* fmw   = (const float*)d_in[9];
    const float* fmb   = (const float*)d_in[10];
    const float* c1w   = (const float*)d_in[11];
    const float* c1b   = (const float*)d_in[12];
    const float* p1w   = (const float*)d_in[13];
    const float* p1b   = (const float*)d_in[14];
    const float* c2w   = (const float*)d_in[15];
    const float* c2b   = (const float*)d_in[16];
    const float* p2w   = (const float*)d_in[17];
    const float* p2b   = (const float*)d_in[18];
    const float* c3w   = (const float*)d_in[19];
    const float* c3b   = (const float*)d_in[20];
    const float* hw    = (const float*)d_in[21];
    const float* hb    = (const float*)d_in[22];

    unsigned int* counter = (unsigned int*)d_ws;          // 4 B used
    float*        tab     = (float*)((char*)d_ws + 64);   // 513 floats

    const int B = in_sizes[0] / 4;                        // 1048576 samples

    // Reset the producer counter every call (captured, deterministic;
    // runtime guarantees inter-dispatch visibility).
    hipMemsetAsync(d_ws, 0, 64, stream);

    int nblocks = B / 1024;                               // 1024
    fused_kernel<<<nblocks, 256, 0, stream>>>(
        (const float4*)x, convw, convb,
        e0w, e0b, e1w, e1b, e2w, e2b, fmw, fmb, c1w, c1b,
        p1w, p1b, c2w, c2b, p2w, p2b, c3w, c3b, hw, hb,
        counter, tab, (float2*)d_out);
}

// Round 6
// 14.774 us; speedup vs baseline: 7.0771x; 2.0588x over previous
//
#include <hip/hip_runtime.h>
#include <math.h>

#define NTAB 256             // table intervals; table has NTAB+1 = 257 entries
#define TLIM 8.0f            // t range [-TLIM, TLIM]

// ---------------------------------------------------------------------------
// Kernel 1: build LUT p(t), 257 entries. 512-thread blocks, 8 waves;
// each wave computes one entry (lane j owns hidden2 row j).
// e1_w (64x128) staged transposed in LDS (stride 65, conflict-free),
// loaded as float4 (4 dwordx4 per thread).
// ---------------------------------------------------------------------------
__global__ __launch_bounds__(512) void build_tab_kernel(
    const float* __restrict__ e0w, const float* __restrict__ e0b,
    const float* __restrict__ e1w, const float* __restrict__ e1b,
    const float* __restrict__ e2w, const float* __restrict__ e2b,
    const float* __restrict__ fmw, const float* __restrict__ fmb,
    const float* __restrict__ c1w, const float* __restrict__ c1b,
    const float* __restrict__ p1w, const float* __restrict__ p1b,
    const float* __restrict__ c2w, const float* __restrict__ c2b,
    const float* __restrict__ p2w, const float* __restrict__ p2b,
    const float* __restrict__ c3w, const float* __restrict__ c3b,
    const float* __restrict__ hw,  const float* __restrict__ hb,
    float* __restrict__ tab)
{
    __shared__ float wt[128 * 65];
    const int tid = threadIdx.x;

    // Stage e1_w transposed: 2048 float4 total, 4 per thread.
    const float4* e1w4 = (const float4*)e1w;
    #pragma unroll
    for (int i = 0; i < 4; ++i) {
        int idx4 = i * 512 + tid;         // 0..2047
        float4 v = e1w4[idx4];
        int base = idx4 * 4;
        int j = base >> 7;                // row 0..63
        int k = base & 127;               // col 0..124 (multiple of 4)
        wt[(k + 0) * 65 + j] = v.x;
        wt[(k + 1) * 65 + j] = v.y;
        wt[(k + 2) * 65 + j] = v.z;
        wt[(k + 3) * 65 + j] = v.w;
    }
    __syncthreads();

    const int wave = tid >> 6;
    const int lane = tid & 63;
    const int e    = blockIdx.x * 8 + wave;       // table entry (0..263)
    const int ec   = (e <= NTAB) ? e : NTAB;      // clamp: uniform math

    const float t  = -TLIM + (2.0f * TLIM) * (float)ec / (float)NTAB;
    const float sv = 1.0f / (1.0f + expf(-t));

    // h2[lane] = relu(sum_k e1w[lane,k]*relu(e0w[k]*sv+e0b[k]) + e1b[lane])
    float a0 = e1b[lane], a1 = 0.0f, a2 = 0.0f, a3 = 0.0f;
    #pragma unroll 4
    for (int k = 0; k < 128; k += 4) {
        float h10 = fmaxf(fmaf(e0w[k + 0], sv, e0b[k + 0]), 0.0f);
        float h11 = fmaxf(fmaf(e0w[k + 1], sv, e0b[k + 1]), 0.0f);
        float h12 = fmaxf(fmaf(e0w[k + 2], sv, e0b[k + 2]), 0.0f);
        float h13 = fmaxf(fmaf(e0w[k + 3], sv, e0b[k + 3]), 0.0f);
        a0 = fmaf(wt[(k + 0) * 65 + lane], h10, a0);
        a1 = fmaf(wt[(k + 1) * 65 + lane], h11, a1);
        a2 = fmaf(wt[(k + 2) * 65 + lane], h12, a2);
        a3 = fmaf(wt[(k + 3) * 65 + lane], h13, a3);
    }
    float h2 = fmaxf((a0 + a1) + (a2 + a3), 0.0f);

    // latent = e2_w (2x64) @ h2 + e2_b : butterfly reduction
    float v0 = e2w[lane] * h2;
    float v1 = e2w[64 + lane] * h2;
    #pragma unroll
    for (int off = 32; off > 0; off >>= 1) {
        v0 += __shfl_xor(v0, off);
        v1 += __shfl_xor(v1, off);
    }
    float l0 = v0 + e2b[0];
    float l1 = v1 + e2b[1];

    // QCNN tanh chain (tiny; redundant per lane)
    float y0[4], y1[4], y2[3], y3[2];
    #pragma unroll
    for (int o = 0; o < 4; ++o)
        y0[o] = tanhf(fmaf(fmw[o*2], l0, fmaf(fmw[o*2+1], l1, fmb[o])));
    #pragma unroll
    for (int o = 0; o < 4; ++o)
        y1[o] = tanhf(fmaf(c1w[o*4], y0[0], fmaf(c1w[o*4+1], y0[1],
                      fmaf(c1w[o*4+2], y0[2], fmaf(c1w[o*4+3], y0[3], c1b[o])))));
    #pragma unroll
    for (int o = 0; o < 3; ++o)
        y2[o] = tanhf(fmaf(p1w[o*4], y1[0], fmaf(p1w[o*4+1], y1[1],
                      fmaf(p1w[o*4+2], y1[2], fmaf(p1w[o*4+3], y1[3], p1b[o])))));
    #pragma unroll
    for (int o = 0; o < 2; ++o)
        y3[o] = tanhf(fmaf(c2w[o*3], y2[0], fmaf(c2w[o*3+1], y2[1],
                      fmaf(c2w[o*3+2], y2[2], c2b[o]))));
    float y4 = tanhf(fmaf(p2w[0], y3[0], fmaf(p2w[1], y3[1], p2b[0])));
    float y5 = tanhf(fmaf(c3w[0], y4, c3b[0]));
    float g0 = fmaf(hw[0], y5, hb[0]);
    float g1 = fmaf(hw[1], y5, hb[1]);
    float p0 = 1.0f / (1.0f + expf(g1 - g0));   // softmax -> sigmoid(g0-g1)

    if (lane == 0 && e <= NTAB) tab[e] = p0;
}

// ---------------------------------------------------------------------------
// Kernel 2: memory-bound eval, 8 samples/thread, 512 blocks.
// All global loads/stores lane-dense. LDS table = exactly 256 (value,delta)
// float2 entries (clamp guarantees k<=255), one entry staged per thread.
// ---------------------------------------------------------------------------
__global__ __launch_bounds__(256) void eval_kernel(
    const float4* __restrict__ x4,
    const float*  __restrict__ convw,
    const float*  __restrict__ convb,
    const float*  __restrict__ tab,
    float2* __restrict__ out2)
{
    __shared__ float2 ltab[NTAB];
    const int tid  = threadIdx.x;
    const int base = blockIdx.x * 2048;   // 2048 samples per block

    // Issue x loads first: 8 dwordx4 in flight per lane during staging.
    float4 xs[8];
    #pragma unroll
    for (int j = 0; j < 8; ++j)
        xs[j] = x4[base + j * 256 + tid];

    // Stage table: one (value, delta) entry per thread.
    {
        float v  = tab[tid];
        float vn = tab[tid + 1];
        ltab[tid] = make_float2(v, vn - v);
    }
    __syncthreads();

    const float scale = (float)NTAB / (2.0f * TLIM);   // 16.0f
    const float w0 = convw[0] * scale, w1 = convw[1] * scale,
                w2 = convw[2] * scale, w3 = convw[3] * scale;
    const float cb = (convb[0] + TLIM) * scale;

    #pragma unroll
    for (int j = 0; j < 8; ++j) {
        float f = fmaf(xs[j].x, w0, fmaf(xs[j].y, w1,
                  fmaf(xs[j].z, w2, fmaf(xs[j].w, w3, cb))));
        f = fminf(fmaxf(f, 0.0f), (float)NTAB - 0.001f);
        int   k = (int)f;
        float r = f - (float)k;
        float2 vd = ltab[k];
        float p = fmaf(r, vd.y, vd.x);
        out2[base + j * 256 + tid] = make_float2(p, 1.0f - p);
    }
}

extern "C" void kernel_launch(void* const* d_in, const int* in_sizes, int n_in,
                              void* d_out, int out_size, void* d_ws, size_t ws_size,
                              hipStream_t stream) {
    const float* x     = (const float*)d_in[0];
    const float* convw = (const float*)d_in[1];
    const float* convb = (const float*)d_in[2];
    const float* e0w   = (const float*)d_in[3];
    const float* e0b   = (const float*)d_in[4];
    const float* e1w   = (const float*)d_in[5];
    const float* e1b   = (const float*)d_in[6];
    const float* e2w   = (const float*)d_in[7];
    const float* e2b   = (const float*)d_in[8];
    const float* fmw   = (const float*)d_in[9];
    const float* fmb   = (const float*)d_in[10];
    const float* c1w   = (const float*)d_in[11];
    const float* c1b   = (const float*)d_in[12];
    const float* p1w   = (const float*)d_in[13];
    const float* p1b   = (const float*)d_in[14];
    const float* c2w   = (const float*)d_in[15];
    const float* c2b   = (const float*)d_in[16];
    const float* p2w   = (const float*)d_in[17];
    const float* p2b   = (const float*)d_in[18];
    const float* c3w   = (const float*)d_in[19];
    const float* c3b   = (const float*)d_in[20];
    const float* hw    = (const float*)d_in[21];
    const float* hb    = (const float*)d_in[22];

    float* tab = (float*)d_ws;                 // 257 floats

    const int B = in_sizes[0] / 4;             // 1048576 samples

    // Build LUT: 8 entries per 512-thread block -> 33 blocks cover 257.
    int nblocks_tab = (NTAB + 1 + 7) / 8;      // 33
    build_tab_kernel<<<nblocks_tab, 512, 0, stream>>>(
        e0w, e0b, e1w, e1b, e2w, e2b, fmw, fmb, c1w, c1b,
        p1w, p1b, c2w, c2b, p2w, p2b, c3w, c3b, hw, hb, tab);

    // Evaluate: 2048 samples per block.
    int nblocks = B / 2048;                    // 512
    eval_kernel<<<nblocks, 256, 0, stream>>>(
        (const float4*)x, convw, convb, tab, (float2*)d_out);
}